// Round 12
// baseline (666.062 us; speedup 1.0000x reference)
//
#include <hip/hip_runtime.h>
#include <hip/hip_fp16.h>

#define NN 100000
#define NE 800000
#define DD 128
#define NL 4
#define NG 512
#define NT 10
#define BN_EPS 1e-5f
#define SCAN_B 1024
#define CHUNK 7

typedef __attribute__((ext_vector_type(4))) float f32x4;
typedef __attribute__((ext_vector_type(8))) _Float16 f16x8;

__device__ __forceinline__ float atomAddF(float* p, float v) {
  return unsafeAtomicAdd(p, v);
}

// -------- edge degree counts + CSR rank (atomicAdd return value) ------------

__global__ __launch_bounds__(256) void edge_count_kernel(
    const int* __restrict__ ei, int* __restrict__ degcnt,
    int* __restrict__ incnt, int* __restrict__ erank) {
  int t = blockIdx.x * 256 + threadIdx.x;
  if (t * 4 >= NE) return;
  int4 s = *reinterpret_cast<const int4*>(&ei[t * 4]);
  int4 d = *reinterpret_cast<const int4*>(&ei[NE + t * 4]);
  atomicAdd(&degcnt[s.x], 1);
  atomicAdd(&degcnt[s.y], 1);
  atomicAdd(&degcnt[s.z], 1);
  atomicAdd(&degcnt[s.w], 1);
  int4 r;
  r.x = atomicAdd(&incnt[d.x], 1);
  r.y = atomicAdd(&incnt[d.y], 1);
  r.z = atomicAdd(&incnt[d.z], 1);
  r.w = atomicAdd(&incnt[d.w], 1);
  *reinterpret_cast<int4*>(&erank[t * 4]) = r;
}

// ---------------- tables: Wf + aemb16 + gstart (binary search) -------

__global__ __launch_bounds__(256) void tables_kernel(
    const float* __restrict__ W, __half* __restrict__ Wf,
    const float* __restrict__ atom_emb, __half* __restrict__ aemb16,
    const int* __restrict__ batch, int* __restrict__ gstart) {
  const int idx = blockIdx.x * 256 + threadIdx.x;
  // W -> fragment-ordered fp16
  if (idx < NL * 8 * 4 * 64) {
    int lane = idx & 63;
    int c = (idx >> 6) & 3;
    int t = (idx >> 8) & 7;
    int l = idx >> 11;
    const float* Wl = W + l * DD * DD;
    __half* o = Wf + idx * 8;
    int n = t * 16 + (lane & 15);
    int k0 = c * 32 + (lane >> 4) * 8;
#pragma unroll
    for (int i = 0; i < 8; ++i) o[i] = (__half)Wl[(k0 + i) * DD + n];
  }
  // atom_emb -> fp16
  if (idx < 9 * 64 * 32) {
    float4 v = *reinterpret_cast<const float4*>(&atom_emb[idx * 4]);
    union { __half2 hh[2]; int2 i2; } u;
    u.hh[0] = __floats2half2_rn(v.x, v.y);
    u.hh[1] = __floats2half2_rn(v.z, v.w);
    *reinterpret_cast<int2*>(&aemb16[idx * 4]) = u.i2;
  }
  // gstart via binary search over sorted batch
  if (idx <= NG) {
    if (idx == NG) {
      gstart[NG] = NN;
    } else {
      int lo = 0, hi = NN;
      while (lo < hi) {
        int m = (lo + hi) >> 1;
        if (batch[m] < idx) lo = m + 1; else hi = m;
      }
      gstart[idx] = lo;
    }
  }
}

// ---------------- atom encoder ----------------

__global__ __launch_bounds__(256) void atom_encoder_kernel(
    const int* __restrict__ x, const __half* __restrict__ aemb16,
    __half* __restrict__ h) {
  __shared__ int xs[16 * 9];
  const int nb = blockIdx.x * 16;
  const int t = threadIdx.x;
  if (t < 144) {
    int gi = nb * 9 + t;
    xs[t] = (gi < NN * 9) ? x[gi] : 0;
  }
  __syncthreads();
  const int n = nb + (t >> 4);
  const int q8 = t & 15;
  if (n >= NN) return;
  const f16x8* av = reinterpret_cast<const f16x8*>(aemb16);
  float acc[8] = {};
#pragma unroll
  for (int f = 0; f < 9; ++f) {
    int r = xs[(t >> 4) * 9 + f];
    f16x8 v = av[(f * 64 + r) * 16 + q8];
#pragma unroll
    for (int i = 0; i < 8; ++i) acc[i] += (float)v[i];
  }
  union { __half2 hh[4]; int4 i4; } u;
#pragma unroll
  for (int i = 0; i < 4; ++i)
    u.hh[i] = __floats2half2_rn(acc[2 * i], acc[2 * i + 1]);
  *reinterpret_cast<int4*>(&h[n * DD + q8 * 8]) = u.i4;
}

// ---------------- CSR build ----------------

__global__ __launch_bounds__(256) void scan1_kernel(
    const int* __restrict__ in, int* __restrict__ out, int* __restrict__ bsum,
    const int* __restrict__ degcnt, float* __restrict__ degrecip,
    float* __restrict__ dinv, int n) {
  __shared__ int s[256];
  int base = blockIdx.x * SCAN_B + threadIdx.x * 4;
  int v[4] = {0, 0, 0, 0};
  if (base + 3 < n) {
    int4 t = *reinterpret_cast<const int4*>(&in[base]);
    v[0] = t.x; v[1] = t.y; v[2] = t.z; v[3] = t.w;
  } else {
    for (int i = 0; i < 4; ++i) v[i] = (base + i < n) ? in[base + i] : 0;
  }
  for (int i = 0; i < 4; ++i) {
    if (base + i < n) {
      float dv = (float)degcnt[base + i] + 1.f;
      degrecip[base + i] = 1.f / dv;
      dinv[base + i] = rsqrtf(dv);
    }
  }
  int tsum = v[0] + v[1] + v[2] + v[3];
  s[threadIdx.x] = tsum;
  __syncthreads();
  for (int d = 1; d < 256; d <<= 1) {
    int t = (threadIdx.x >= d) ? s[threadIdx.x - d] : 0;
    __syncthreads();
    s[threadIdx.x] += t;
    __syncthreads();
  }
  int run = s[threadIdx.x] - tsum;
  if (threadIdx.x == 255) bsum[blockIdx.x] = s[255];
  for (int i = 0; i < 4; ++i) {
    if (base + i < n) out[base + i] = run;
    run += v[i];
  }
}

__global__ void scan2_kernel(int* bsum, int nb) {
  __shared__ int s[128];
  int v = (threadIdx.x < nb) ? bsum[threadIdx.x] : 0;
  s[threadIdx.x] = v;
  __syncthreads();
  for (int d = 1; d < 128; d <<= 1) {
    int t = (threadIdx.x >= d) ? s[threadIdx.x - d] : 0;
    __syncthreads();
    s[threadIdx.x] += t;
    __syncthreads();
  }
  if (threadIdx.x < nb) bsum[threadIdx.x] = s[threadIdx.x] - v;
}

__global__ __launch_bounds__(256) void scan3_kernel(int* off, const int* bsum,
                                                    int n, int total) {
  int i = blockIdx.x * 256 + threadIdx.x;
  if (i < n) off[i] += bsum[i / SCAN_B];
  if (i == 0) off[n] = total;
}

// packed edge record: {src(17b) | idx9<<17, norm_bits} — no atomics (erank)
__global__ __launch_bounds__(256) void csr_fill_kernel(
    const int* __restrict__ ei, const int* __restrict__ eattr,
    const float* __restrict__ dinv, const int* __restrict__ off,
    const int* __restrict__ erank, int2* __restrict__ edata) {
  int e = blockIdx.x * 256 + threadIdx.x;
  if (e >= NE) return;
  int r = ei[e], c = ei[NE + e];
  int pos = off[c] + erank[e];
  float nm = dinv[r] * dinv[c];
  int idx9 = eattr[e * 3] | (eattr[e * 3 + 1] << 3) | (eattr[e * 3 + 2] << 6);
  int2 d;
  d.x = r | (idx9 << 17);
  d.y = __float_as_int(nm);
  edata[pos] = d;
}

// ---------------- MFMA GEMM: hl = act(A) @ W + bias (fp16 in/out) ----------------

__global__ __launch_bounds__(256) void gemm_mfma_kernel(
    const __half* __restrict__ A, const __half* __restrict__ Wf,
    const float* __restrict__ bias, const float* __restrict__ bn_scale,
    const float* __restrict__ bn_shift, int fuse_bn, __half* __restrict__ hl) {
  const int wid = threadIdx.x >> 6, lane = threadIdx.x & 63;
  const int r0 = blockIdx.x * 64 + wid * 16;
  const int arow = min(r0 + (lane & 15), NN - 1);
  const int kb = (lane >> 4) * 8;

  f16x8 afrag[4];
#pragma unroll
  for (int c = 0; c < 4; ++c) {
    const int k0 = c * 32 + kb;
    f16x8 raw = *reinterpret_cast<const f16x8*>(&A[arow * DD + k0]);
    if (fuse_bn) {
#pragma unroll
      for (int i = 0; i < 8; ++i) {
        float v = fmaxf((float)raw[i] * bn_scale[k0 + i] + bn_shift[k0 + i], 0.f);
        raw[i] = (_Float16)v;
      }
    }
    afrag[c] = raw;
  }

  f32x4 acc[8];
#pragma unroll
  for (int t = 0; t < 8; ++t) acc[t] = (f32x4){0.f, 0.f, 0.f, 0.f};

  const f16x8* __restrict__ wf = reinterpret_cast<const f16x8*>(Wf);
#pragma unroll
  for (int t = 0; t < 8; ++t) {
#pragma unroll
    for (int c = 0; c < 4; ++c) {
      f16x8 b = wf[(t * 4 + c) * 64 + lane];
      acc[t] = __builtin_amdgcn_mfma_f32_16x16x32_f16(afrag[c], b, acc[t], 0, 0, 0);
    }
  }

  const int colb = lane & 15;
  const int rbase = r0 + (lane >> 4) * 4;
#pragma unroll
  for (int t = 0; t < 8; ++t) {
    float bb = bias[t * 16 + colb];
#pragma unroll
    for (int j = 0; j < 4; ++j) {
      int row = rbase + j;
      if (row < NN) hl[row * DD + t * 16 + colb] = (__half)(acc[t][j] + bb);
    }
  }
}

// ---------------- fused gather + update + BN stats / pool ----------------
// 256 thr, 4 waves, CHUNK=7 (3572 blocks), fp16 bond table in LDS (6KB).

#define PROC(E)                                                       \
  {                                                                   \
    int p_ = (E).x;                                                   \
    float nm_ = __int_as_float((E).y);                                \
    float2 hv_ = __half22float2(hl2[(p_ & 0x1FFFF) * 64 + lane]);     \
    int i9_ = p_ >> 17;                                               \
    float2 b0_ = __half22float2(bembS[(i9_ & 7) * 64 + lane]);        \
    float2 b1_ = __half22float2(bembS[(8 + ((i9_ >> 3) & 7)) * 64 + lane]); \
    float2 b2_ = __half22float2(bembS[(16 + ((i9_ >> 6) & 7)) * 64 + lane]); \
    acc0 += nm_ * fmaxf(hv_.x + b0_.x + b1_.x + b2_.x, 0.f);          \
    acc1 += nm_ * fmaxf(hv_.y + b0_.y + b1_.y + b2_.y, 0.f);          \
  }

__global__ __launch_bounds__(256) void gather_update_kernel(
    const int* __restrict__ off, const int2* __restrict__ edata,
    const __half2* __restrict__ hl2, const float* __restrict__ bemb,
    const float* __restrict__ root, const float* __restrict__ degrecip,
    const int* __restrict__ batch, __half2* __restrict__ h2,
    float* __restrict__ hg, float* __restrict__ bn_sum,
    float* __restrict__ bn_sq, int mode) {  // mode 0: h+stats, 1: pool
  __shared__ __half2 bembS[24 * 64];
  const float2* bemb2 = reinterpret_cast<const float2*>(bemb);
  for (int i = threadIdx.x; i < 24 * 64; i += 256) {
    float2 v = bemb2[i];
    bembS[i] = __floats2half2_rn(v.x, v.y);
  }
  const int wid = threadIdx.x >> 6;
  const int lane = threadIdx.x & 63;
  float2 rt = *reinterpret_cast<const float2*>(&root[2 * lane]);
  float ls0 = 0, ls1 = 0, lq0 = 0, lq1 = 0;
  const int wv = blockIdx.x * 4 + wid;
  const int n0 = wv * CHUNK;
  const int n1 = min(n0 + CHUNK, NN);
  int curg = -1;
  float pg0 = 0.f, pg1 = 0.f;
  __syncthreads();
  for (int n = n0; n < n1; ++n) {
    int k0 = off[n], k1 = off[n + 1];
    float acc0 = 0.f, acc1 = 0.f;
    int k = k0;
    for (; k + 3 < k1; k += 4) {
      int2 e0 = edata[k], e1 = edata[k + 1], e2 = edata[k + 2],
           e3 = edata[k + 3];
      PROC(e0) PROC(e1) PROC(e2) PROC(e3)
    }
    for (; k < k1; ++k) {
      int2 e0 = edata[k];
      PROC(e0)
    }
    float dr = degrecip[n];
    float2 hs = __half22float2(hl2[n * 64 + lane]);
    float v0 = acc0 + fmaxf(hs.x + rt.x, 0.f) * dr;
    float v1 = acc1 + fmaxf(hs.y + rt.y, 0.f) * dr;
    if (mode == 0) {
      h2[n * 64 + lane] = __floats2half2_rn(v0, v1);
      ls0 += v0; ls1 += v1;
      lq0 += v0 * v0; lq1 += v1 * v1;
    } else {
      int g = batch[n];
      if (g != curg) {
        if (curg >= 0) {
          atomAddF(&hg[curg * DD + 2 * lane], pg0);
          atomAddF(&hg[curg * DD + 2 * lane + 1], pg1);
        }
        curg = g;
        pg0 = v0; pg1 = v1;
      } else {
        pg0 += v0; pg1 += v1;
      }
    }
  }
  if (mode == 1) {
    if (curg >= 0) {
      atomAddF(&hg[curg * DD + 2 * lane], pg0);
      atomAddF(&hg[curg * DD + 2 * lane + 1], pg1);
    }
    return;
  }
  __shared__ float s0[DD], s1[DD];
  const int d0 = 2 * lane, d1 = 2 * lane + 1;
  if (wid == 0) {
    s0[d0] = ls0; s0[d1] = ls1;
    s1[d0] = lq0; s1[d1] = lq1;
  }
  __syncthreads();
#pragma unroll
  for (int w = 1; w < 4; ++w) {
    if (wid == w) {
      s0[d0] += ls0; s0[d1] += ls1;
      s1[d0] += lq0; s1[d1] += lq1;
    }
    __syncthreads();
  }
  if (threadIdx.x < DD) {
    atomAddF(&bn_sum[threadIdx.x], s0[threadIdx.x]);
    atomAddF(&bn_sq[threadIdx.x], s1[threadIdx.x]);
  }
}

__global__ __launch_bounds__(128) void bn_finalize_kernel(
    const float* __restrict__ bn_sum, const float* __restrict__ bn_sq,
    const float* __restrict__ gamma, const float* __restrict__ beta,
    float* __restrict__ scale, float* __restrict__ shift) {
  int d = threadIdx.x;
  float mu = bn_sum[d] / (float)NN;
  float var = bn_sq[d] / (float)NN - mu * mu;
  float inv = rsqrtf(var + BN_EPS);
  float sc = gamma[d] * inv;
  scale[d] = sc;
  shift[d] = beta[d] - mu * sc;
}

// ---------------- MLP on pooled features ----------------

__global__ __launch_bounds__(128) void mlp_kernel(
    const float* __restrict__ hg, const int* __restrict__ gstart,
    const float* __restrict__ W1, const float* __restrict__ b1,
    const float* __restrict__ W2, const float* __restrict__ b2,
    float* __restrict__ out) {
  int g = blockIdx.x, t = threadIdx.x;
  float cnt = fmaxf((float)(gstart[g + 1] - gstart[g]), 1.f);
  __shared__ float row[DD], t1[DD];
  row[t] = fmaxf(hg[g * DD + t] / cnt, 0.f);
  __syncthreads();
  float a1v = b1[t];
  for (int k = 0; k < DD; ++k) a1v = fmaf(row[k], W1[k * DD + t], a1v);
  t1[t] = fmaxf(a1v, 0.f);
  __syncthreads();
  if (t < NT) {
    float a2 = b2[t];
    for (int k = 0; k < DD; ++k) a2 = fmaf(t1[k], W2[k * NT + t], a2);
    out[g * NT + t] = a2;
  }
}

extern "C" void kernel_launch(void* const* d_in, const int* in_sizes, int n_in,
                              void* d_out, int out_size, void* d_ws,
                              size_t ws_size, hipStream_t stream) {
  const int* x = (const int*)d_in[0];
  const int* edge_index = (const int*)d_in[1];
  const int* batch = (const int*)d_in[2];
  const int* edge_attr = (const int*)d_in[3];
  const float* atom_emb = (const float*)d_in[4];
  const float* W = (const float*)d_in[5];
  const float* b = (const float*)d_in[6];
  const float* root = (const float*)d_in[7];
  const float* bond_emb = (const float*)d_in[8];
  const float* gamma = (const float*)d_in[9];
  const float* beta = (const float*)d_in[10];
  const float* W1 = (const float*)d_in[11];
  const float* b1 = (const float*)d_in[12];
  const float* W2 = (const float*)d_in[13];
  const float* b2 = (const float*)d_in[14];
  float* out = (float*)d_out;

  char* ws = (char*)d_ws;
  size_t off_b = 0;
  auto alloc = [&](size_t bytes) {
    char* p = ws + off_b;
    off_b += (bytes + 255) & ~size_t(255);
    return p;
  };
  __half* h = (__half*)alloc(sizeof(__half) * NN * DD);
  __half* hl = (__half*)alloc(sizeof(__half) * NN * DD);
  int2* edata = (int2*)alloc(sizeof(int2) * NE);
  int* erank = (int*)alloc(sizeof(int) * NE);
  float* degrecip = (float*)alloc(sizeof(float) * NN);
  float* dinv = (float*)alloc(sizeof(float) * NN);
  int* off = (int*)alloc(sizeof(int) * (NN + 1));
  int* bsum = (int*)alloc(sizeof(int) * 128);
  float* bsc = (float*)alloc(sizeof(float) * DD);
  float* bsh = (float*)alloc(sizeof(float) * DD);
  int* gstart = (int*)alloc(sizeof(int) * (NG + 1));
  __half* Wf = (__half*)alloc(sizeof(__half) * NL * DD * DD);
  __half* aemb16 = (__half*)alloc(sizeof(__half) * 9 * 64 * DD);
  // ---- contiguous zero region ----
  char* zstart = ws + off_b;
  int* degcnt = (int*)alloc(sizeof(int) * NN);
  int* incnt = (int*)alloc(sizeof(int) * NN);
  float* hg = (float*)alloc(sizeof(float) * NG * DD);
  float* bnS = (float*)alloc(sizeof(float) * NL * DD);
  float* bnQ = (float*)alloc(sizeof(float) * NL * DD);
  size_t zbytes = (ws + off_b) - zstart;

  hipMemsetAsync(zstart, 0, zbytes, stream);

  edge_count_kernel<<<(NE / 4 + 255) / 256, 256, 0, stream>>>(
      edge_index, degcnt, incnt, erank);
  tables_kernel<<<(9 * 64 * 32 + 255) / 256, 256, 0, stream>>>(
      W, Wf, atom_emb, aemb16, batch, gstart);
  atom_encoder_kernel<<<(NN * 16 + 255) / 256, 256, 0, stream>>>(x, aemb16, h);

  const int nb = (NN + SCAN_B - 1) / SCAN_B;  // 98
  scan1_kernel<<<nb, 256, 0, stream>>>(incnt, off, bsum, degcnt, degrecip,
                                       dinv, NN);
  scan2_kernel<<<1, 128, 0, stream>>>(bsum, nb);
  scan3_kernel<<<(NN + 255) / 256, 256, 0, stream>>>(off, bsum, NN, NE);
  csr_fill_kernel<<<(NE + 255) / 256, 256, 0, stream>>>(edge_index, edge_attr,
                                                        dinv, off, erank, edata);

  const int GB = (NN + 4 * CHUNK - 1) / (4 * CHUNK);  // 3572 blocks
  for (int l = 0; l < NL; ++l) {
    gemm_mfma_kernel<<<(NN + 63) / 64, 256, 0, stream>>>(
        h, Wf + l * DD * DD, b + l * DD, bsc, bsh, l > 0 ? 1 : 0, hl);
    int mode = (l < NL - 1) ? 0 : 1;
    gather_update_kernel<<<GB, 256, 0, stream>>>(
        off, edata, (const __half2*)hl, bond_emb + l * 3 * 8 * DD,
        root + l * DD, degrecip, batch, (__half2*)h, hg, bnS + l * DD,
        bnQ + l * DD, mode);
    if (mode == 0) {
      bn_finalize_kernel<<<1, DD, 0, stream>>>(bnS + l * DD, bnQ + l * DD,
                                               gamma + l * DD, beta + l * DD,
                                               bsc, bsh);
    }
  }

  mlp_kernel<<<NG, DD, 0, stream>>>(hg, gstart, W1, b1, W2, b2, out);
}

// Round 13
// 574.599 us; speedup vs baseline: 1.1592x; 1.1592x over previous
//
#include <hip/hip_runtime.h>
#include <hip/hip_fp16.h>

#define NN 100000
#define NE 800000
#define DD 128
#define NL 4
#define NG 512
#define NT 10
#define BN_EPS 1e-5f
#define SCAN_B 1024
#define CHUNK 7

typedef __attribute__((ext_vector_type(4))) float f32x4;
typedef __attribute__((ext_vector_type(8))) _Float16 f16x8;

__device__ __forceinline__ float atomAddF(float* p, float v) {
  return unsafeAtomicAdd(p, v);
}

// -------- edge degree counts + CSR rank (atomicAdd return value) ------------

__global__ __launch_bounds__(256) void edge_count_kernel(
    const int* __restrict__ ei, int* __restrict__ degcnt,
    int* __restrict__ incnt, int* __restrict__ erank) {
  int t = blockIdx.x * 256 + threadIdx.x;
  if (t * 4 >= NE) return;
  int4 s = *reinterpret_cast<const int4*>(&ei[t * 4]);
  int4 d = *reinterpret_cast<const int4*>(&ei[NE + t * 4]);
  atomicAdd(&degcnt[s.x], 1);
  atomicAdd(&degcnt[s.y], 1);
  atomicAdd(&degcnt[s.z], 1);
  atomicAdd(&degcnt[s.w], 1);
  int4 r;
  r.x = atomicAdd(&incnt[d.x], 1);
  r.y = atomicAdd(&incnt[d.y], 1);
  r.z = atomicAdd(&incnt[d.z], 1);
  r.w = atomicAdd(&incnt[d.w], 1);
  *reinterpret_cast<int4*>(&erank[t * 4]) = r;
}

// ---------------- tables: Wf + aemb16 + gstart (binary search) -------

__global__ __launch_bounds__(256) void tables_kernel(
    const float* __restrict__ W, __half* __restrict__ Wf,
    const float* __restrict__ atom_emb, __half* __restrict__ aemb16,
    const int* __restrict__ batch, int* __restrict__ gstart) {
  const int idx = blockIdx.x * 256 + threadIdx.x;
  if (idx < NL * 8 * 4 * 64) {
    int lane = idx & 63;
    int c = (idx >> 6) & 3;
    int t = (idx >> 8) & 7;
    int l = idx >> 11;
    const float* Wl = W + l * DD * DD;
    __half* o = Wf + idx * 8;
    int n = t * 16 + (lane & 15);
    int k0 = c * 32 + (lane >> 4) * 8;
#pragma unroll
    for (int i = 0; i < 8; ++i) o[i] = (__half)Wl[(k0 + i) * DD + n];
  }
  if (idx < 9 * 64 * 32) {
    float4 v = *reinterpret_cast<const float4*>(&atom_emb[idx * 4]);
    union { __half2 hh[2]; int2 i2; } u;
    u.hh[0] = __floats2half2_rn(v.x, v.y);
    u.hh[1] = __floats2half2_rn(v.z, v.w);
    *reinterpret_cast<int2*>(&aemb16[idx * 4]) = u.i2;
  }
  if (idx <= NG) {
    if (idx == NG) {
      gstart[NG] = NN;
    } else {
      int lo = 0, hi = NN;
      while (lo < hi) {
        int m = (lo + hi) >> 1;
        if (batch[m] < idx) lo = m + 1; else hi = m;
      }
      gstart[idx] = lo;
    }
  }
}

// ---------------- atom encoder ----------------

__global__ __launch_bounds__(256) void atom_encoder_kernel(
    const int* __restrict__ x, const __half* __restrict__ aemb16,
    __half* __restrict__ h) {
  __shared__ int xs[16 * 9];
  const int nb = blockIdx.x * 16;
  const int t = threadIdx.x;
  if (t < 144) {
    int gi = nb * 9 + t;
    xs[t] = (gi < NN * 9) ? x[gi] : 0;
  }
  __syncthreads();
  const int n = nb + (t >> 4);
  const int q8 = t & 15;
  if (n >= NN) return;
  const f16x8* av = reinterpret_cast<const f16x8*>(aemb16);
  float acc[8] = {};
#pragma unroll
  for (int f = 0; f < 9; ++f) {
    int r = xs[(t >> 4) * 9 + f];
    f16x8 v = av[(f * 64 + r) * 16 + q8];
#pragma unroll
    for (int i = 0; i < 8; ++i) acc[i] += (float)v[i];
  }
  union { __half2 hh[4]; int4 i4; } u;
#pragma unroll
  for (int i = 0; i < 4; ++i)
    u.hh[i] = __floats2half2_rn(acc[2 * i], acc[2 * i + 1]);
  *reinterpret_cast<int4*>(&h[n * DD + q8 * 8]) = u.i4;
}

// ---------------- CSR build ----------------

__global__ __launch_bounds__(256) void scan1_kernel(
    const int* __restrict__ in, int* __restrict__ out, int* __restrict__ bsum,
    const int* __restrict__ degcnt, float* __restrict__ degrecip,
    float* __restrict__ dinv, int n) {
  __shared__ int s[256];
  int base = blockIdx.x * SCAN_B + threadIdx.x * 4;
  int v[4] = {0, 0, 0, 0};
  if (base + 3 < n) {
    int4 t = *reinterpret_cast<const int4*>(&in[base]);
    v[0] = t.x; v[1] = t.y; v[2] = t.z; v[3] = t.w;
  } else {
    for (int i = 0; i < 4; ++i) v[i] = (base + i < n) ? in[base + i] : 0;
  }
  for (int i = 0; i < 4; ++i) {
    if (base + i < n) {
      float dv = (float)degcnt[base + i] + 1.f;
      degrecip[base + i] = 1.f / dv;
      dinv[base + i] = rsqrtf(dv);
    }
  }
  int tsum = v[0] + v[1] + v[2] + v[3];
  s[threadIdx.x] = tsum;
  __syncthreads();
  for (int d = 1; d < 256; d <<= 1) {
    int t = (threadIdx.x >= d) ? s[threadIdx.x - d] : 0;
    __syncthreads();
    s[threadIdx.x] += t;
    __syncthreads();
  }
  int run = s[threadIdx.x] - tsum;
  if (threadIdx.x == 255) bsum[blockIdx.x] = s[255];
  for (int i = 0; i < 4; ++i) {
    if (base + i < n) out[base + i] = run;
    run += v[i];
  }
}

__global__ void scan2_kernel(int* bsum, int nb) {
  __shared__ int s[128];
  int v = (threadIdx.x < nb) ? bsum[threadIdx.x] : 0;
  s[threadIdx.x] = v;
  __syncthreads();
  for (int d = 1; d < 128; d <<= 1) {
    int t = (threadIdx.x >= d) ? s[threadIdx.x - d] : 0;
    __syncthreads();
    s[threadIdx.x] += t;
    __syncthreads();
  }
  if (threadIdx.x < nb) bsum[threadIdx.x] = s[threadIdx.x] - v;
}

__global__ __launch_bounds__(256) void scan3_kernel(int* off, const int* bsum,
                                                    int n, int total) {
  int i = blockIdx.x * 256 + threadIdx.x;
  if (i < n) off[i] += bsum[i / SCAN_B];
  if (i == 0) off[n] = total;
}

// packed edge record: {src(17b) | idx9<<17, norm_bits} — no atomics (erank)
__global__ __launch_bounds__(256) void csr_fill_kernel(
    const int* __restrict__ ei, const int* __restrict__ eattr,
    const float* __restrict__ dinv, const int* __restrict__ off,
    const int* __restrict__ erank, int2* __restrict__ edata) {
  int e = blockIdx.x * 256 + threadIdx.x;
  if (e >= NE) return;
  int r = ei[e], c = ei[NE + e];
  int pos = off[c] + erank[e];
  float nm = dinv[r] * dinv[c];
  int idx9 = eattr[e * 3] | (eattr[e * 3 + 1] << 3) | (eattr[e * 3 + 2] << 6);
  int2 d;
  d.x = r | (idx9 << 17);
  d.y = __float_as_int(nm);
  edata[pos] = d;
}

// ---------------- MFMA GEMM: hl = act(A) @ W + bias (fp16 in/out) ----------------

__global__ __launch_bounds__(256) void gemm_mfma_kernel(
    const __half* __restrict__ A, const __half* __restrict__ Wf,
    const float* __restrict__ bias, const float* __restrict__ bn_scale,
    const float* __restrict__ bn_shift, int fuse_bn, __half* __restrict__ hl) {
  const int wid = threadIdx.x >> 6, lane = threadIdx.x & 63;
  const int r0 = blockIdx.x * 64 + wid * 16;
  const int arow = min(r0 + (lane & 15), NN - 1);
  const int kb = (lane >> 4) * 8;

  f16x8 afrag[4];
#pragma unroll
  for (int c = 0; c < 4; ++c) {
    const int k0 = c * 32 + kb;
    f16x8 raw = *reinterpret_cast<const f16x8*>(&A[arow * DD + k0]);
    if (fuse_bn) {
#pragma unroll
      for (int i = 0; i < 8; ++i) {
        float v = fmaxf((float)raw[i] * bn_scale[k0 + i] + bn_shift[k0 + i], 0.f);
        raw[i] = (_Float16)v;
      }
    }
    afrag[c] = raw;
  }

  f32x4 acc[8];
#pragma unroll
  for (int t = 0; t < 8; ++t) acc[t] = (f32x4){0.f, 0.f, 0.f, 0.f};

  const f16x8* __restrict__ wf = reinterpret_cast<const f16x8*>(Wf);
#pragma unroll
  for (int t = 0; t < 8; ++t) {
#pragma unroll
    for (int c = 0; c < 4; ++c) {
      f16x8 b = wf[(t * 4 + c) * 64 + lane];
      acc[t] = __builtin_amdgcn_mfma_f32_16x16x32_f16(afrag[c], b, acc[t], 0, 0, 0);
    }
  }

  const int colb = lane & 15;
  const int rbase = r0 + (lane >> 4) * 4;
#pragma unroll
  for (int t = 0; t < 8; ++t) {
    float bb = bias[t * 16 + colb];
#pragma unroll
    for (int j = 0; j < 4; ++j) {
      int row = rbase + j;
      if (row < NN) hl[row * DD + t * 16 + colb] = (__half)(acc[t][j] + bb);
    }
  }
}

// ---------------- fused gather + update + BN stats / pool ----------------
// DUAL-STREAM: 8 half-wave streams per 256-thr block; half-lane owns 4 ch.
// fp32 bond table in LDS (12KB, float2 reads). Predicated 4x unroll.

__global__ __launch_bounds__(256) void gather_update_kernel(
    const int* __restrict__ off, const int2* __restrict__ edata,
    const __half2* __restrict__ hl2, const float* __restrict__ bemb,
    const float* __restrict__ root, const float* __restrict__ degrecip,
    const int* __restrict__ batch, __half2* __restrict__ h2,
    float* __restrict__ hg, float* __restrict__ bn_sum,
    float* __restrict__ bn_sq, int mode) {  // mode 0: h+stats, 1: pool
  __shared__ float2 bembS[24 * 64];
  __shared__ float s0[DD], s1[DD];
  const float2* bemb2 = reinterpret_cast<const float2*>(bemb);
  for (int i = threadIdx.x; i < 24 * 64; i += 256) bembS[i] = bemb2[i];
  if (mode == 0 && threadIdx.x < DD) {
    s0[threadIdx.x] = 0.f;
    s1[threadIdx.x] = 0.f;
  }
  const int sid = threadIdx.x >> 5;   // stream 0..7
  const int sl = threadIdx.x & 31;    // half-lane
  const int p0 = 2 * sl;              // half2-pair base (channels 4sl..4sl+3)
  float4 rt = *reinterpret_cast<const float4*>(&root[4 * sl]);
  float ls[4] = {0, 0, 0, 0}, lq[4] = {0, 0, 0, 0};
  const int wv = blockIdx.x * 8 + sid;
  const int n0 = wv * CHUNK;
  const int n1 = min(n0 + CHUNK, NN);
  int curg = -1;
  float pg[4] = {0, 0, 0, 0};
  __syncthreads();
  for (int n = n0; n < n1; ++n) {
    int k0 = off[n], k1 = off[n + 1];
    int cnt = k1 - k0;
    int mx = max(cnt, __shfl_xor(cnt, 32));
    float a0 = 0.f, a1 = 0.f, a2 = 0.f, a3 = 0.f;
    for (int i = 0; i < mx; i += 4) {
      int2 e[4];
#pragma unroll
      for (int j = 0; j < 4; ++j) e[j] = edata[min(k0 + i + j, NE - 1)];
      int2 hv[4];
#pragma unroll
      for (int j = 0; j < 4; ++j)
        hv[j] = *reinterpret_cast<const int2*>(&hl2[(e[j].x & 0x1FFFF) * 64 + p0]);
#pragma unroll
      for (int j = 0; j < 4; ++j) {
        float nm = ((i + j) < cnt) ? __int_as_float(e[j].y) : 0.f;
        int i9 = e[j].x >> 17;
        float2 h01 = __half22float2(*reinterpret_cast<__half2*>(&hv[j].x));
        float2 h23 = __half22float2(*reinterpret_cast<__half2*>(&hv[j].y));
        const float2* t0 = &bembS[(i9 & 7) * 64];
        const float2* t1 = &bembS[(8 + ((i9 >> 3) & 7)) * 64];
        const float2* t2 = &bembS[(16 + ((i9 >> 6) & 7)) * 64];
        float2 b0a = t0[p0], b0b = t0[p0 + 1];
        float2 b1a = t1[p0], b1b = t1[p0 + 1];
        float2 b2a = t2[p0], b2b = t2[p0 + 1];
        a0 += nm * fmaxf(h01.x + b0a.x + b1a.x + b2a.x, 0.f);
        a1 += nm * fmaxf(h01.y + b0a.y + b1a.y + b2a.y, 0.f);
        a2 += nm * fmaxf(h23.x + b0b.x + b1b.x + b2b.x, 0.f);
        a3 += nm * fmaxf(h23.y + b0b.y + b1b.y + b2b.y, 0.f);
      }
    }
    float dr = degrecip[n];
    int2 hs2 = *reinterpret_cast<const int2*>(&hl2[n * 64 + p0]);
    float2 hs01 = __half22float2(*reinterpret_cast<__half2*>(&hs2.x));
    float2 hs23 = __half22float2(*reinterpret_cast<__half2*>(&hs2.y));
    float v0 = a0 + fmaxf(hs01.x + rt.x, 0.f) * dr;
    float v1 = a1 + fmaxf(hs01.y + rt.y, 0.f) * dr;
    float v2 = a2 + fmaxf(hs23.x + rt.z, 0.f) * dr;
    float v3 = a3 + fmaxf(hs23.y + rt.w, 0.f) * dr;
    if (mode == 0) {
      int2 o;
      *reinterpret_cast<__half2*>(&o.x) = __floats2half2_rn(v0, v1);
      *reinterpret_cast<__half2*>(&o.y) = __floats2half2_rn(v2, v3);
      *reinterpret_cast<int2*>(&h2[n * 64 + p0]) = o;
      ls[0] += v0; ls[1] += v1; ls[2] += v2; ls[3] += v3;
      lq[0] += v0 * v0; lq[1] += v1 * v1; lq[2] += v2 * v2; lq[3] += v3 * v3;
    } else {
      int g = batch[n];
      if (g != curg) {
        if (curg >= 0) {
#pragma unroll
          for (int j = 0; j < 4; ++j)
            atomAddF(&hg[curg * DD + 4 * sl + j], pg[j]);
        }
        curg = g;
        pg[0] = v0; pg[1] = v1; pg[2] = v2; pg[3] = v3;
      } else {
        pg[0] += v0; pg[1] += v1; pg[2] += v2; pg[3] += v3;
      }
    }
  }
  if (mode == 1) {
    if (curg >= 0) {
#pragma unroll
      for (int j = 0; j < 4; ++j)
        atomAddF(&hg[curg * DD + 4 * sl + j], pg[j]);
    }
    return;
  }
#pragma unroll
  for (int j = 0; j < 4; ++j) {
    atomicAdd(&s0[4 * sl + j], ls[j]);
    atomicAdd(&s1[4 * sl + j], lq[j]);
  }
  __syncthreads();
  if (threadIdx.x < DD) {
    atomAddF(&bn_sum[threadIdx.x], s0[threadIdx.x]);
    atomAddF(&bn_sq[threadIdx.x], s1[threadIdx.x]);
  }
}

__global__ __launch_bounds__(128) void bn_finalize_kernel(
    const float* __restrict__ bn_sum, const float* __restrict__ bn_sq,
    const float* __restrict__ gamma, const float* __restrict__ beta,
    float* __restrict__ scale, float* __restrict__ shift) {
  int d = threadIdx.x;
  float mu = bn_sum[d] / (float)NN;
  float var = bn_sq[d] / (float)NN - mu * mu;
  float inv = rsqrtf(var + BN_EPS);
  float sc = gamma[d] * inv;
  scale[d] = sc;
  shift[d] = beta[d] - mu * sc;
}

// ---------------- MLP on pooled features ----------------

__global__ __launch_bounds__(128) void mlp_kernel(
    const float* __restrict__ hg, const int* __restrict__ gstart,
    const float* __restrict__ W1, const float* __restrict__ b1,
    const float* __restrict__ W2, const float* __restrict__ b2,
    float* __restrict__ out) {
  int g = blockIdx.x, t = threadIdx.x;
  float cnt = fmaxf((float)(gstart[g + 1] - gstart[g]), 1.f);
  __shared__ float row[DD], t1[DD];
  row[t] = fmaxf(hg[g * DD + t] / cnt, 0.f);
  __syncthreads();
  float a1v = b1[t];
  for (int k = 0; k < DD; ++k) a1v = fmaf(row[k], W1[k * DD + t], a1v);
  t1[t] = fmaxf(a1v, 0.f);
  __syncthreads();
  if (t < NT) {
    float a2 = b2[t];
    for (int k = 0; k < DD; ++k) a2 = fmaf(t1[k], W2[k * NT + t], a2);
    out[g * NT + t] = a2;
  }
}

extern "C" void kernel_launch(void* const* d_in, const int* in_sizes, int n_in,
                              void* d_out, int out_size, void* d_ws,
                              size_t ws_size, hipStream_t stream) {
  const int* x = (const int*)d_in[0];
  const int* edge_index = (const int*)d_in[1];
  const int* batch = (const int*)d_in[2];
  const int* edge_attr = (const int*)d_in[3];
  const float* atom_emb = (const float*)d_in[4];
  const float* W = (const float*)d_in[5];
  const float* b = (const float*)d_in[6];
  const float* root = (const float*)d_in[7];
  const float* bond_emb = (const float*)d_in[8];
  const float* gamma = (const float*)d_in[9];
  const float* beta = (const float*)d_in[10];
  const float* W1 = (const float*)d_in[11];
  const float* b1 = (const float*)d_in[12];
  const float* W2 = (const float*)d_in[13];
  const float* b2 = (const float*)d_in[14];
  float* out = (float*)d_out;

  char* ws = (char*)d_ws;
  size_t off_b = 0;
  auto alloc = [&](size_t bytes) {
    char* p = ws + off_b;
    off_b += (bytes + 255) & ~size_t(255);
    return p;
  };
  __half* h = (__half*)alloc(sizeof(__half) * NN * DD);
  __half* hl = (__half*)alloc(sizeof(__half) * NN * DD);
  int2* edata = (int2*)alloc(sizeof(int2) * NE);
  int* erank = (int*)alloc(sizeof(int) * NE);
  float* degrecip = (float*)alloc(sizeof(float) * NN);
  float* dinv = (float*)alloc(sizeof(float) * NN);
  int* off = (int*)alloc(sizeof(int) * (NN + 1));
  int* bsum = (int*)alloc(sizeof(int) * 128);
  float* bsc = (float*)alloc(sizeof(float) * DD);
  float* bsh = (float*)alloc(sizeof(float) * DD);
  int* gstart = (int*)alloc(sizeof(int) * (NG + 1));
  __half* Wf = (__half*)alloc(sizeof(__half) * NL * DD * DD);
  __half* aemb16 = (__half*)alloc(sizeof(__half) * 9 * 64 * DD);
  // ---- contiguous zero region ----
  char* zstart = ws + off_b;
  int* degcnt = (int*)alloc(sizeof(int) * NN);
  int* incnt = (int*)alloc(sizeof(int) * NN);
  float* hg = (float*)alloc(sizeof(float) * NG * DD);
  float* bnS = (float*)alloc(sizeof(float) * NL * DD);
  float* bnQ = (float*)alloc(sizeof(float) * NL * DD);
  size_t zbytes = (ws + off_b) - zstart;

  hipMemsetAsync(zstart, 0, zbytes, stream);

  edge_count_kernel<<<(NE / 4 + 255) / 256, 256, 0, stream>>>(
      edge_index, degcnt, incnt, erank);
  tables_kernel<<<(9 * 64 * 32 + 255) / 256, 256, 0, stream>>>(
      W, Wf, atom_emb, aemb16, batch, gstart);
  atom_encoder_kernel<<<(NN * 16 + 255) / 256, 256, 0, stream>>>(x, aemb16, h);

  const int nb = (NN + SCAN_B - 1) / SCAN_B;  // 98
  scan1_kernel<<<nb, 256, 0, stream>>>(incnt, off, bsum, degcnt, degrecip,
                                       dinv, NN);
  scan2_kernel<<<1, 128, 0, stream>>>(bsum, nb);
  scan3_kernel<<<(NN + 255) / 256, 256, 0, stream>>>(off, bsum, NN, NE);
  csr_fill_kernel<<<(NE + 255) / 256, 256, 0, stream>>>(edge_index, edge_attr,
                                                        dinv, off, erank, edata);

  const int GB = (NN + 8 * CHUNK - 1) / (8 * CHUNK);  // 1786 blocks
  for (int l = 0; l < NL; ++l) {
    gemm_mfma_kernel<<<(NN + 63) / 64, 256, 0, stream>>>(
        h, Wf + l * DD * DD, b + l * DD, bsc, bsh, l > 0 ? 1 : 0, hl);
    int mode = (l < NL - 1) ? 0 : 1;
    gather_update_kernel<<<GB, 256, 0, stream>>>(
        off, edata, (const __half2*)hl, bond_emb + l * 3 * 8 * DD,
        root + l * DD, degrecip, batch, (__half2*)h, hg, bnS + l * DD,
        bnQ + l * DD, mode);
    if (mode == 0) {
      bn_finalize_kernel<<<1, DD, 0, stream>>>(bnS + l * DD, bnQ + l * DD,
                                               gamma + l * DD, beta + l * DD,
                                               bsc, bsh);
    }
  }

  mlp_kernel<<<NG, DD, 0, stream>>>(hg, gstart, W1, b1, W2, b2, out);
}

// Round 15
// 560.247 us; speedup vs baseline: 1.1889x; 1.0256x over previous
//
#include <hip/hip_runtime.h>
#include <hip/hip_fp16.h>

#define NN 100000
#define NE 800000
#define DD 128
#define NL 4
#define NG 512
#define NT 10
#define BN_EPS 1e-5f
#define SCAN_B 1024
#define CHUNK 7

typedef __attribute__((ext_vector_type(4))) float f32x4;
typedef __attribute__((ext_vector_type(8))) _Float16 f16x8;

#define EB 3125    // edge-count blocks (1 edge/thread)
#define TB 72      // table blocks
#define AB 12500   // atom-encoder blocks (8 nodes/block, 32 thr/node)
#define GB0 1563   // gemm-l0 blocks in FAT2
#define CB 3125    // csr_fill blocks in FAT2

__device__ __forceinline__ float atomAddF(float* p, float v) {
  return unsafeAtomicAdd(p, v);
}

// ---------------- FAT1: edge_count ∥ tables ∥ atom_encoder ----------------
// NO intra-kernel data deps: every job reads only kernel inputs.

__global__ __launch_bounds__(256) void fat1_kernel(
    const int* __restrict__ ei, int* __restrict__ degcnt,
    int* __restrict__ incnt, int* __restrict__ erank,
    const float* __restrict__ W, __half* __restrict__ Wf,
    const int* __restrict__ batch, int* __restrict__ gstart,
    const int* __restrict__ x, const float* __restrict__ atom_emb,
    __half* __restrict__ h) {
  __shared__ int xs[8 * 9];
  const int bid = blockIdx.x;
  const int t = threadIdx.x;
  if (bid < EB) {
    // ---- edge degree counts + rank ----
    int e = bid * 256 + t;  // EB*256 == NE exactly
    int s = ei[e], d = ei[NE + e];
    atomicAdd(&degcnt[s], 1);
    erank[e] = atomicAdd(&incnt[d], 1);
    return;
  }
  if (bid < EB + TB) {
    const int idx = (bid - EB) * 256 + t;
    if (idx < NL * 8 * 4 * 64) {  // W -> fragment-ordered fp16
      int lane = idx & 63;
      int c = (idx >> 6) & 3;
      int tt = (idx >> 8) & 7;
      int l = idx >> 11;
      const float* Wl = W + l * DD * DD;
      __half* o = Wf + idx * 8;
      int n = tt * 16 + (lane & 15);
      int k0 = c * 32 + (lane >> 4) * 8;
#pragma unroll
      for (int i = 0; i < 8; ++i) o[i] = (__half)Wl[(k0 + i) * DD + n];
    }
    if (idx <= NG) {  // gstart via binary search over sorted batch
      if (idx == NG) {
        gstart[NG] = NN;
      } else {
        int lo = 0, hi = NN;
        while (lo < hi) {
          int m = (lo + hi) >> 1;
          if (batch[m] < idx) lo = m + 1; else hi = m;
        }
        gstart[idx] = lo;
      }
    }
    return;
  }
  // ---- atom encoder: 32 thr/node, fp32 table read (kernel input) ----
  const int nb = (bid - EB - TB) * 8;
  if (t < 72) {
    int gi = nb * 9 + t;
    xs[t] = (gi < NN * 9) ? x[gi] : 0;
  }
  __syncthreads();
  const int n = nb + (t >> 5);
  const int q = t & 31;
  if (n >= NN) return;
  float4 acc = make_float4(0.f, 0.f, 0.f, 0.f);
#pragma unroll
  for (int f = 0; f < 9; ++f) {
    int r = xs[(t >> 5) * 9 + f];
    float4 v = *reinterpret_cast<const float4*>(&atom_emb[(f * 64 + r) * DD + q * 4]);
    acc.x += v.x; acc.y += v.y; acc.z += v.z; acc.w += v.w;
  }
  union { __half2 hh[2]; int2 i2; } u;
  u.hh[0] = __floats2half2_rn(acc.x, acc.y);
  u.hh[1] = __floats2half2_rn(acc.z, acc.w);
  *reinterpret_cast<int2*>(&h[n * DD + q * 4]) = u.i2;
}

// ---------------- CSR scans ----------------

__global__ __launch_bounds__(256) void scan1_kernel(
    const int* __restrict__ in, int* __restrict__ out, int* __restrict__ bsum,
    const int* __restrict__ degcnt, float* __restrict__ degrecip,
    float* __restrict__ dinv, int n) {
  __shared__ int s[256];
  int base = blockIdx.x * SCAN_B + threadIdx.x * 4;
  int v[4] = {0, 0, 0, 0};
  if (base + 3 < n) {
    int4 t = *reinterpret_cast<const int4*>(&in[base]);
    v[0] = t.x; v[1] = t.y; v[2] = t.z; v[3] = t.w;
  } else {
    for (int i = 0; i < 4; ++i) v[i] = (base + i < n) ? in[base + i] : 0;
  }
  for (int i = 0; i < 4; ++i) {
    if (base + i < n) {
      float dv = (float)degcnt[base + i] + 1.f;
      degrecip[base + i] = 1.f / dv;
      dinv[base + i] = rsqrtf(dv);
    }
  }
  int tsum = v[0] + v[1] + v[2] + v[3];
  s[threadIdx.x] = tsum;
  __syncthreads();
  for (int d = 1; d < 256; d <<= 1) {
    int t = (threadIdx.x >= d) ? s[threadIdx.x - d] : 0;
    __syncthreads();
    s[threadIdx.x] += t;
    __syncthreads();
  }
  int run = s[threadIdx.x] - tsum;
  if (threadIdx.x == 255) bsum[blockIdx.x] = s[255];
  for (int i = 0; i < 4; ++i) {
    if (base + i < n) out[base + i] = run;
    run += v[i];
  }
}

__global__ void scan2_kernel(int* bsum, int nb) {
  __shared__ int s[128];
  int v = (threadIdx.x < nb) ? bsum[threadIdx.x] : 0;
  s[threadIdx.x] = v;
  __syncthreads();
  for (int d = 1; d < 128; d <<= 1) {
    int t = (threadIdx.x >= d) ? s[threadIdx.x - d] : 0;
    __syncthreads();
    s[threadIdx.x] += t;
    __syncthreads();
  }
  if (threadIdx.x < nb) bsum[threadIdx.x] = s[threadIdx.x] - v;
}

__global__ __launch_bounds__(256) void scan3_kernel(int* off, const int* bsum,
                                                    int n, int total) {
  int i = blockIdx.x * 256 + threadIdx.x;
  if (i < n) off[i] += bsum[i / SCAN_B];
  if (i == 0) off[n] = total;
}

// ---------------- FAT2: gemm layer-0 ∥ csr_fill ----------------

__device__ __forceinline__ void gemm_body(
    int blk, int tid, const __half* __restrict__ A, const __half* __restrict__ Wf,
    const float* __restrict__ bias, const float* __restrict__ bn_scale,
    const float* __restrict__ bn_shift, int fuse_bn, __half* __restrict__ hl) {
  const int wid = tid >> 6, lane = tid & 63;
  const int r0 = blk * 64 + wid * 16;
  const int arow = min(r0 + (lane & 15), NN - 1);
  const int kb = (lane >> 4) * 8;

  f16x8 afrag[4];
#pragma unroll
  for (int c = 0; c < 4; ++c) {
    const int k0 = c * 32 + kb;
    f16x8 raw = *reinterpret_cast<const f16x8*>(&A[arow * DD + k0]);
    if (fuse_bn) {
#pragma unroll
      for (int i = 0; i < 8; ++i) {
        float v = fmaxf((float)raw[i] * bn_scale[k0 + i] + bn_shift[k0 + i], 0.f);
        raw[i] = (_Float16)v;
      }
    }
    afrag[c] = raw;
  }

  f32x4 acc[8];
#pragma unroll
  for (int t = 0; t < 8; ++t) acc[t] = (f32x4){0.f, 0.f, 0.f, 0.f};

  const f16x8* __restrict__ wf = reinterpret_cast<const f16x8*>(Wf);
#pragma unroll
  for (int t = 0; t < 8; ++t) {
#pragma unroll
    for (int c = 0; c < 4; ++c) {
      f16x8 b = wf[(t * 4 + c) * 64 + lane];
      acc[t] = __builtin_amdgcn_mfma_f32_16x16x32_f16(afrag[c], b, acc[t], 0, 0, 0);
    }
  }

  const int colb = lane & 15;
  const int rbase = r0 + (lane >> 4) * 4;
#pragma unroll
  for (int t = 0; t < 8; ++t) {
    float bb = bias[t * 16 + colb];
#pragma unroll
    for (int j = 0; j < 4; ++j) {
      int row = rbase + j;
      if (row < NN) hl[row * DD + t * 16 + colb] = (__half)(acc[t][j] + bb);
    }
  }
}

__global__ __launch_bounds__(256) void fat2_kernel(
    const __half* __restrict__ A, const __half* __restrict__ Wf,
    const float* __restrict__ bias, __half* __restrict__ hl,
    const int* __restrict__ ei, const int* __restrict__ eattr,
    const float* __restrict__ dinv, const int* __restrict__ off,
    const int* __restrict__ erank, int2* __restrict__ edata) {
  const int bid = blockIdx.x;
  if (bid < GB0) {
    gemm_body(bid, threadIdx.x, A, Wf, bias, nullptr, nullptr, 0, hl);
    return;
  }
  int e = (bid - GB0) * 256 + threadIdx.x;
  if (e >= NE) return;
  int r = ei[e], c = ei[NE + e];
  int pos = off[c] + erank[e];
  float nm = dinv[r] * dinv[c];
  int idx9 = eattr[e * 3] | (eattr[e * 3 + 1] << 3) | (eattr[e * 3 + 2] << 6);
  int2 d;
  d.x = r | (idx9 << 17);
  d.y = __float_as_int(nm);
  edata[pos] = d;
}

__global__ __launch_bounds__(256) void gemm_mfma_kernel(
    const __half* __restrict__ A, const __half* __restrict__ Wf,
    const float* __restrict__ bias, const float* __restrict__ bn_scale,
    const float* __restrict__ bn_shift, __half* __restrict__ hl) {
  gemm_body(blockIdx.x, threadIdx.x, A, Wf, bias, bn_scale, bn_shift, 1, hl);
}

// ---------------- fused gather + update + BN stats / pool ----------------
// DUAL-STREAM: 8 half-wave streams per 256-thr block; half-lane owns 4 ch.

__global__ __launch_bounds__(256) void gather_update_kernel(
    const int* __restrict__ off, const int2* __restrict__ edata,
    const __half2* __restrict__ hl2, const float* __restrict__ bemb,
    const float* __restrict__ root, const float* __restrict__ degrecip,
    const int* __restrict__ batch, __half2* __restrict__ h2,
    float* __restrict__ hg, float* __restrict__ bn_sum,
    float* __restrict__ bn_sq, int mode) {  // mode 0: h+stats, 1: pool
  __shared__ float2 bembS[24 * 64];
  __shared__ float s0[DD], s1[DD];
  const float2* bemb2 = reinterpret_cast<const float2*>(bemb);
  for (int i = threadIdx.x; i < 24 * 64; i += 256) bembS[i] = bemb2[i];
  if (mode == 0 && threadIdx.x < DD) {
    s0[threadIdx.x] = 0.f;
    s1[threadIdx.x] = 0.f;
  }
  const int sid = threadIdx.x >> 5;
  const int sl = threadIdx.x & 31;
  const int p0 = 2 * sl;
  float4 rt = *reinterpret_cast<const float4*>(&root[4 * sl]);
  float ls[4] = {0, 0, 0, 0}, lq[4] = {0, 0, 0, 0};
  const int wv = blockIdx.x * 8 + sid;
  const int n0 = wv * CHUNK;
  const int n1 = min(n0 + CHUNK, NN);
  int curg = -1;
  float pg[4] = {0, 0, 0, 0};
  __syncthreads();
  for (int n = n0; n < n1; ++n) {
    int k0 = off[n], k1 = off[n + 1];
    int cnt = k1 - k0;
    int mx = max(cnt, __shfl_xor(cnt, 32));
    float a0 = 0.f, a1 = 0.f, a2 = 0.f, a3 = 0.f;
    for (int i = 0; i < mx; i += 4) {
      int2 e[4];
#pragma unroll
      for (int j = 0; j < 4; ++j) e[j] = edata[min(k0 + i + j, NE - 1)];
      int2 hv[4];
#pragma unroll
      for (int j = 0; j < 4; ++j)
        hv[j] = *reinterpret_cast<const int2*>(&hl2[(e[j].x & 0x1FFFF) * 64 + p0]);
#pragma unroll
      for (int j = 0; j < 4; ++j) {
        float nm = ((i + j) < cnt) ? __int_as_float(e[j].y) : 0.f;
        int i9 = e[j].x >> 17;
        float2 h01 = __half22float2(*reinterpret_cast<__half2*>(&hv[j].x));
        float2 h23 = __half22float2(*reinterpret_cast<__half2*>(&hv[j].y));
        const float2* t0 = &bembS[(i9 & 7) * 64];
        const float2* t1 = &bembS[(8 + ((i9 >> 3) & 7)) * 64];
        const float2* t2 = &bembS[(16 + ((i9 >> 6) & 7)) * 64];
        float2 b0a = t0[p0], b0b = t0[p0 + 1];
        float2 b1a = t1[p0], b1b = t1[p0 + 1];
        float2 b2a = t2[p0], b2b = t2[p0 + 1];
        a0 += nm * fmaxf(h01.x + b0a.x + b1a.x + b2a.x, 0.f);
        a1 += nm * fmaxf(h01.y + b0a.y + b1a.y + b2a.y, 0.f);
        a2 += nm * fmaxf(h23.x + b0b.x + b1b.x + b2b.x, 0.f);
        a3 += nm * fmaxf(h23.y + b0b.y + b1b.y + b2b.y, 0.f);
      }
    }
    float dr = degrecip[n];
    int2 hs2 = *reinterpret_cast<const int2*>(&hl2[n * 64 + p0]);
    float2 hs01 = __half22float2(*reinterpret_cast<__half2*>(&hs2.x));
    float2 hs23 = __half22float2(*reinterpret_cast<__half2*>(&hs2.y));
    float v0 = a0 + fmaxf(hs01.x + rt.x, 0.f) * dr;
    float v1 = a1 + fmaxf(hs01.y + rt.y, 0.f) * dr;
    float v2 = a2 + fmaxf(hs23.x + rt.z, 0.f) * dr;
    float v3 = a3 + fmaxf(hs23.y + rt.w, 0.f) * dr;
    if (mode == 0) {
      int2 o;
      *reinterpret_cast<__half2*>(&o.x) = __floats2half2_rn(v0, v1);
      *reinterpret_cast<__half2*>(&o.y) = __floats2half2_rn(v2, v3);
      *reinterpret_cast<int2*>(&h2[n * 64 + p0]) = o;
      ls[0] += v0; ls[1] += v1; ls[2] += v2; ls[3] += v3;
      lq[0] += v0 * v0; lq[1] += v1 * v1; lq[2] += v2 * v2; lq[3] += v3 * v3;
    } else {
      int g = batch[n];
      if (g != curg) {
        if (curg >= 0) {
#pragma unroll
          for (int j = 0; j < 4; ++j)
            atomAddF(&hg[curg * DD + 4 * sl + j], pg[j]);
        }
        curg = g;
        pg[0] = v0; pg[1] = v1; pg[2] = v2; pg[3] = v3;
      } else {
        pg[0] += v0; pg[1] += v1; pg[2] += v2; pg[3] += v3;
      }
    }
  }
  if (mode == 1) {
    if (curg >= 0) {
#pragma unroll
      for (int j = 0; j < 4; ++j)
        atomAddF(&hg[curg * DD + 4 * sl + j], pg[j]);
    }
    return;
  }
#pragma unroll
  for (int j = 0; j < 4; ++j) {
    atomicAdd(&s0[4 * sl + j], ls[j]);
    atomicAdd(&s1[4 * sl + j], lq[j]);
  }
  __syncthreads();
  if (threadIdx.x < DD) {
    atomAddF(&bn_sum[threadIdx.x], s0[threadIdx.x]);
    atomAddF(&bn_sq[threadIdx.x], s1[threadIdx.x]);
  }
}

__global__ __launch_bounds__(128) void bn_finalize_kernel(
    const float* __restrict__ bn_sum, const float* __restrict__ bn_sq,
    const float* __restrict__ gamma, const float* __restrict__ beta,
    float* __restrict__ scale, float* __restrict__ shift) {
  int d = threadIdx.x;
  float mu = bn_sum[d] / (float)NN;
  float var = bn_sq[d] / (float)NN - mu * mu;
  float inv = rsqrtf(var + BN_EPS);
  float sc = gamma[d] * inv;
  scale[d] = sc;
  shift[d] = beta[d] - mu * sc;
}

// ---------------- MLP on pooled features ----------------

__global__ __launch_bounds__(128) void mlp_kernel(
    const float* __restrict__ hg, const int* __restrict__ gstart,
    const float* __restrict__ W1, const float* __restrict__ b1,
    const float* __restrict__ W2, const float* __restrict__ b2,
    float* __restrict__ out) {
  int g = blockIdx.x, t = threadIdx.x;
  float cnt = fmaxf((float)(gstart[g + 1] - gstart[g]), 1.f);
  __shared__ float row[DD], t1[DD];
  row[t] = fmaxf(hg[g * DD + t] / cnt, 0.f);
  __syncthreads();
  float a1v = b1[t];
  for (int k = 0; k < DD; ++k) a1v = fmaf(row[k], W1[k * DD + t], a1v);
  t1[t] = fmaxf(a1v, 0.f);
  __syncthreads();
  if (t < NT) {
    float a2 = b2[t];
    for (int k = 0; k < DD; ++k) a2 = fmaf(t1[k], W2[k * NT + t], a2);
    out[g * NT + t] = a2;
  }
}

extern "C" void kernel_launch(void* const* d_in, const int* in_sizes, int n_in,
                              void* d_out, int out_size, void* d_ws,
                              size_t ws_size, hipStream_t stream) {
  const int* x = (const int*)d_in[0];
  const int* edge_index = (const int*)d_in[1];
  const int* batch = (const int*)d_in[2];
  const int* edge_attr = (const int*)d_in[3];
  const float* atom_emb = (const float*)d_in[4];
  const float* W = (const float*)d_in[5];
  const float* b = (const float*)d_in[6];
  const float* root = (const float*)d_in[7];
  const float* bond_emb = (const float*)d_in[8];
  const float* gamma = (const float*)d_in[9];
  const float* beta = (const float*)d_in[10];
  const float* W1 = (const float*)d_in[11];
  const float* b1 = (const float*)d_in[12];
  const float* W2 = (const float*)d_in[13];
  const float* b2 = (const float*)d_in[14];
  float* out = (float*)d_out;

  char* ws = (char*)d_ws;
  size_t off_b = 0;
  auto alloc = [&](size_t bytes) {
    char* p = ws + off_b;
    off_b += (bytes + 255) & ~size_t(255);
    return p;
  };
  __half* h = (__half*)alloc(sizeof(__half) * NN * DD);
  __half* hl = (__half*)alloc(sizeof(__half) * NN * DD);
  int2* edata = (int2*)alloc(sizeof(int2) * NE);
  int* erank = (int*)alloc(sizeof(int) * NE);
  float* degrecip = (float*)alloc(sizeof(float) * NN);
  float* dinv = (float*)alloc(sizeof(float) * NN);
  int* off = (int*)alloc(sizeof(int) * (NN + 1));
  int* bsum = (int*)alloc(sizeof(int) * 128);
  float* bsc = (float*)alloc(sizeof(float) * DD);
  float* bsh = (float*)alloc(sizeof(float) * DD);
  int* gstart = (int*)alloc(sizeof(int) * (NG + 1));
  __half* Wf = (__half*)alloc(sizeof(__half) * NL * DD * DD);
  // ---- contiguous zero region ----
  char* zstart = ws + off_b;
  int* degcnt = (int*)alloc(sizeof(int) * NN);
  int* incnt = (int*)alloc(sizeof(int) * NN);
  float* hg = (float*)alloc(sizeof(float) * NG * DD);
  float* bnS = (float*)alloc(sizeof(float) * NL * DD);
  float* bnQ = (float*)alloc(sizeof(float) * NL * DD);
  size_t zbytes = (ws + off_b) - zstart;

  hipMemsetAsync(zstart, 0, zbytes, stream);

  fat1_kernel<<<EB + TB + AB, 256, 0, stream>>>(
      edge_index, degcnt, incnt, erank, W, Wf, batch, gstart, x, atom_emb, h);

  const int nb = (NN + SCAN_B - 1) / SCAN_B;  // 98
  scan1_kernel<<<nb, 256, 0, stream>>>(incnt, off, bsum, degcnt, degrecip,
                                       dinv, NN);
  scan2_kernel<<<1, 128, 0, stream>>>(bsum, nb);
  scan3_kernel<<<(NN + 255) / 256, 256, 0, stream>>>(off, bsum, NN, NE);

  // FAT2: gemm layer-0 ∥ csr_fill
  fat2_kernel<<<GB0 + CB, 256, 0, stream>>>(h, Wf, b, hl, edge_index,
                                            edge_attr, dinv, off, erank, edata);

  const int GB = (NN + 8 * CHUNK - 1) / (8 * CHUNK);  // 1786 blocks
  for (int l = 0; l < NL; ++l) {
    if (l > 0) {
      gemm_mfma_kernel<<<(NN + 63) / 64, 256, 0, stream>>>(
          h, Wf + l * DD * DD, b + l * DD, bsc, bsh, hl);
    }
    int mode = (l < NL - 1) ? 0 : 1;
    gather_update_kernel<<<GB, 256, 0, stream>>>(
        off, edata, (const __half2*)hl, bond_emb + l * 3 * 8 * DD,
        root + l * DD, degrecip, batch, (__half2*)h, hg, bnS + l * DD,
        bnQ + l * DD, mode);
    if (mode == 0) {
      bn_finalize_kernel<<<1, DD, 0, stream>>>(bnS + l * DD, bnQ + l * DD,
                                               gamma + l * DD, beta + l * DD,
                                               bsc, bsh);
    }
  }

  mlp_kernel<<<NG, DD, 0, stream>>>(hg, gstart, W1, b1, W2, b2, out);
}